// Round 6
// baseline (325.819 us; speedup 1.0000x reference)
//
#include <hip/hip_runtime.h>
#include <hip/hip_bf16.h>
#include <math.h>

#define S_LEN 2048
#define BATCH 2
#define NH 16
#define DK 64
#define DM 1024
#define BS (BATCH * S_LEN)       /* 4096 rows */
#define BHS (BATCH * NH * S_LEN) /* 65536 head-rows */
#define TRP 72                   /* transpose-buffer pitch (shorts): 144B rows keep b128 aligned */
#define PSTR 72

using bf16x8  = __attribute__((ext_vector_type(8))) __bf16;
using floatx4 = __attribute__((ext_vector_type(4))) float;
using ushort4v = __attribute__((ext_vector_type(4))) unsigned short;

extern "C" __device__ float __ocml_exp2_f32(float);

__device__ __forceinline__ unsigned short f2bf(float f) {
    union { float f; unsigned u; } v; v.f = f;
    unsigned r = v.u + 0x7fffu + ((v.u >> 16) & 1u);
    return (unsigned short)(r >> 16);
}

// packed RNE f32x2 -> bf16x2 (single VOP3)
__device__ __forceinline__ unsigned cvt_pk_bf16(float a, float b) {
    unsigned r;
    asm("v_cvt_pk_bf16_f32 %0, %1, %2" : "=v"(r) : "v"(a), "v"(b));
    return r;
}

__device__ __forceinline__ float fast_tanh(float x) {
    float e = __ocml_exp2_f32(x * 2.8853900817779268f);
    return 1.0f - 2.0f / (e + 1.0f);
}

// async global->LDS, 16 bytes per lane. LDS dest must be wave-uniform base + lane*16.
__device__ __forceinline__ void gl2lds16(const void* g, void* l) {
    __builtin_amdgcn_global_load_lds(
        (__attribute__((address_space(1))) void*)(uintptr_t)g,
        (__attribute__((address_space(3))) void*)(uintptr_t)l,
        16, 0, 0);
}

// ---------------- prep: fp32 -> bf16 convert for Q,K,V ----------------
__global__ void k_convert(const float* __restrict__ q, const float* __restrict__ k,
                          const float* __restrict__ v,
                          unsigned short* __restrict__ qb, unsigned short* __restrict__ kb,
                          unsigned short* __restrict__ vb) {
    const int N4 = BS * DM / 4;
    int i = blockIdx.x * 256 + threadIdx.x;
    int which = i / N4;
    int off = i - which * N4;
    const floatx4* src = (const floatx4*)(which == 0 ? q : which == 1 ? k : v);
    unsigned short* dst = which == 0 ? qb : which == 1 ? kb : vb;
    floatx4 x = src[off];
    ushort4v o;
    unsigned p01 = cvt_pk_bf16(x[0], x[1]);
    unsigned p23 = cvt_pk_bf16(x[2], x[3]);
    o[0] = (unsigned short)p01; o[1] = (unsigned short)(p01 >> 16);
    o[2] = (unsigned short)p23; o[3] = (unsigned short)(p23 >> 16);
    ((ushort4v*)dst)[off] = o;
}

// ---------------- prep: transpose square fp32 matrix -> bf16 [N][K] ----------------
__global__ void k_transpose(const float* s0, const float* s1, const float* s2, const float* s3,
                            unsigned short* d0, unsigned short* d1, unsigned short* d2,
                            unsigned short* d3, int n) {
    int z = blockIdx.z;
    const float* src = z == 0 ? s0 : z == 1 ? s1 : z == 2 ? s2 : s3;
    unsigned short* dst = z == 0 ? d0 : z == 1 ? d1 : z == 2 ? d2 : d3;
    __shared__ unsigned short tile[32][33];
    int tx = threadIdx.x & 31, ty = threadIdx.x >> 5;
#pragma unroll
    for (int i = 0; i < 4; i++) {
        int y = blockIdx.y * 32 + i * 8 + ty;
        tile[i * 8 + ty][tx] = f2bf(src[(size_t)y * n + blockIdx.x * 32 + tx]);
    }
    __syncthreads();
#pragma unroll
    for (int i = 0; i < 4; i++) {
        int r = blockIdx.x * 32 + i * 8 + ty;
        dst[(size_t)r * n + blockIdx.y * 32 + tx] = tile[tx][i * 8 + ty];
    }
}

// ---------------- prep: pack mask int32 -> bitmask ----------------
__global__ void k_maskpack(const int* __restrict__ mask, unsigned int* __restrict__ mb) {
    int t = blockIdx.x * 256 + threadIdx.x;
    int row = t >> 6, w = t & 63;
    const int* p = mask + (size_t)row * S_LEN + w * 32;
    unsigned bits = 0;
#pragma unroll
    for (int i = 0; i < 32; i++) bits |= (p[i] != 0 ? 1u : 0u) << i;
    mb[t] = bits;
}

// ---------------- merged QKV projection GEMM + fused feature map ----------------
// z==0: qfb row-major [bh][s][dk], = tanh(proj@wnq+bnq) * log2e/(8*temp[h])
// z==1: kfrag fragment order, = tanh(proj@wnk+bnk)
// z==2: vfrag in PV-fragment order
__global__ __launch_bounds__(256) void k_gemm_qkv(
    const unsigned short* __restrict__ Qb, const unsigned short* __restrict__ Kb,
    const unsigned short* __restrict__ Vb,
    const unsigned short* __restrict__ Wqt, const unsigned short* __restrict__ Wkt,
    const unsigned short* __restrict__ Wvt,
    const float* __restrict__ bq, const float* __restrict__ bk, const float* __restrict__ bv,
    const unsigned short* __restrict__ wnqt, const unsigned short* __restrict__ wnkt,
    const float* __restrict__ bnq, const float* __restrict__ bnk,
    const float* __restrict__ temp,
    unsigned short* __restrict__ qfb, unsigned short* __restrict__ kfrag,
    unsigned short* __restrict__ vfrag) {
    const int K = DM;
    int z = blockIdx.z;
    const unsigned short* A  = z == 0 ? Qb  : z == 1 ? Kb  : Vb;
    const unsigned short* Wt = z == 0 ? Wqt : z == 1 ? Wkt : Wvt;
    const float* bias        = z == 0 ? bq  : z == 1 ? bk  : bv;
    int m0 = blockIdx.y * 128, n0 = blockIdx.x * 128;
    __shared__ unsigned short As[128 * 32];
    __shared__ unsigned short Bs[128 * 32];
    __shared__ unsigned short Tr[4][32 * TRP];
    int tid = threadIdx.x;
    int lane = tid & 63, wid = tid >> 6;
    int wy = wid >> 1, wx = wid & 1;
    int l16 = lane & 15, quad = lane >> 4;

    floatx4 acc[4][4] = {};

    for (int kt = 0; kt < K / 32; kt++) {
        int kk = kt * 32;
#pragma unroll
        for (int i = 0; i < 2; i++) {
            int c = i * 256 + tid;
            int row = c >> 2, seg = c & 3;
            gl2lds16(A + (size_t)(m0 + row) * K + kk + seg * 8, &As[c * 8]);
            gl2lds16(Wt + (size_t)(n0 + row) * K + kk + seg * 8, &Bs[c * 8]);
        }
        __syncthreads();
        bf16x8 af[4], bf[4];
#pragma unroll
        for (int mi = 0; mi < 4; mi++)
            af[mi] = *(const bf16x8*)&As[(wy * 64 + mi * 16 + l16) * 32 + quad * 8];
#pragma unroll
        for (int ni = 0; ni < 4; ni++)
            bf[ni] = *(const bf16x8*)&Bs[(wx * 64 + ni * 16 + l16) * 32 + quad * 8];
#pragma unroll
        for (int mi = 0; mi < 4; mi++)
#pragma unroll
            for (int ni = 0; ni < 4; ni++)
                acc[mi][ni] = __builtin_amdgcn_mfma_f32_16x16x32_bf16(af[mi], bf[ni], acc[mi][ni], 0, 0, 0);
        __syncthreads();
    }

    float bvv[4];
#pragma unroll
    for (int ni = 0; ni < 4; ni++) bvv[ni] = bias[n0 + wx * 64 + ni * 16 + l16];
    int head = (n0 + wx * 64) >> 6;
    int mbase = m0 + wy * 64;
    int b = mbase >> 11;
    int bh = b * NH + head;
    unsigned short* tw = &Tr[wid][0];

    if (z == 2) {
        int kt2 = (mbase & (S_LEN - 1)) >> 6;
        size_t tilebase = ((size_t)bh * 32 + kt2) * 4096;
#pragma unroll
        for (int hh = 0; hh < 2; hh++) {
#pragma unroll
            for (int ni2 = 0; ni2 < 2; ni2++) {
                int ni = hh * 2 + ni2;
#pragma unroll
                for (int mi = 0; mi < 4; mi++) {
                    unsigned p01 = cvt_pk_bf16(acc[mi][ni][0] + bvv[ni], acc[mi][ni][1] + bvv[ni]);
                    unsigned p23 = cvt_pk_bf16(acc[mi][ni][2] + bvv[ni], acc[mi][ni][3] + bvv[ni]);
                    int ad = (ni2 * 16 + l16) * TRP + mi * 16 + quad * 4;
                    *(unsigned*)&tw[ad] = p01;
                    *(unsigned*)&tw[ad + 2] = p23;
                }
            }
#pragma unroll
            for (int c = 0; c < 4; c++) {
                int ad = ((c >> 1) * 16 + l16) * TRP + (c & 1) * 32 + quad * 8;
                bf16x8 vv = *(const bf16x8*)&tw[ad];
                *(bf16x8*)&vfrag[tilebase + (size_t)(4 * hh + c) * 512 + lane * 8] = vv;
            }
        }
    } else {
        const unsigned short* wn = z == 0 ? wnqt : wnkt;
        const float* bn = z == 0 ? bnq : bnk;
        float sc = z == 0 ? 1.4426950408889634f / (8.0f * temp[head]) : 1.0f;
        bf16x8 wf[4][2];
        float bnv[4];
#pragma unroll
        for (int ni = 0; ni < 4; ni++) {
            bnv[ni] = bn[ni * 16 + l16];
#pragma unroll
            for (int ks = 0; ks < 2; ks++)
                wf[ni][ks] = *(const bf16x8*)(wn + (size_t)(ni * 16 + l16) * DK + ks * 32 + quad * 8);
        }
        size_t rowbase = (size_t)((size_t)bh * S_LEN + (mbase & (S_LEN - 1))) * DK;
        int kt2 = (mbase & (S_LEN - 1)) >> 6;
        size_t tb = ((size_t)bh * 32 + kt2) * 4096;
#pragma unroll
        for (int hh = 0; hh < 2; hh++) {
            // 1) projection rows (+bias) -> Tr [m][d]
#pragma unroll
            for (int mi2 = 0; mi2 < 2; mi2++) {
                int mi = hh * 2 + mi2;
#pragma unroll
                for (int ni = 0; ni < 4; ni++) {
                    unsigned p01 = cvt_pk_bf16(acc[mi][ni][0] + bvv[ni], acc[mi][ni][1] + bvv[ni]);
                    unsigned p23 = cvt_pk_bf16(acc[mi][ni][2] + bvv[ni], acc[mi][ni][3] + bvv[ni]);
                    int ad = (mi2 * 16 + quad * 4) * TRP + ni * 16 + l16;
                    tw[ad] = (unsigned short)p01;
                    tw[ad + TRP] = (unsigned short)(p01 >> 16);
                    tw[ad + 2 * TRP] = (unsigned short)p23;
                    tw[ad + 3 * TRP] = (unsigned short)(p23 >> 16);
                }
            }
            // 2) feature GEMM from Tr A-frags (own wave slice; DS ops wave-ordered)
            floatx4 facc[2][4] = {};
#pragma unroll
            for (int mg = 0; mg < 2; mg++) {
                bf16x8 af2[2];
#pragma unroll
                for (int ks = 0; ks < 2; ks++)
                    af2[ks] = *(const bf16x8*)&tw[(mg * 16 + l16) * TRP + ks * 32 + quad * 8];
#pragma unroll
                for (int ni = 0; ni < 4; ni++) {
                    facc[mg][ni] = __builtin_amdgcn_mfma_f32_16x16x32_bf16(af2[0], wf[ni][0], facc[mg][ni], 0, 0, 0);
                    facc[mg][ni] = __builtin_amdgcn_mfma_f32_16x16x32_bf16(af2[1], wf[ni][1], facc[mg][ni], 0, 0, 0);
                }
            }
            // 3) tanh(+bias)*sc -> Tr [m][d']
#pragma unroll
            for (int mg = 0; mg < 2; mg++) {
#pragma unroll
                for (int ni = 0; ni < 4; ni++) {
                    float t0 = fast_tanh(facc[mg][ni][0] + bnv[ni]) * sc;
                    float t1 = fast_tanh(facc[mg][ni][1] + bnv[ni]) * sc;
                    float t2 = fast_tanh(facc[mg][ni][2] + bnv[ni]) * sc;
                    float t3 = fast_tanh(facc[mg][ni][3] + bnv[ni]) * sc;
                    unsigned p01 = cvt_pk_bf16(t0, t1);
                    unsigned p23 = cvt_pk_bf16(t2, t3);
                    int ad = (mg * 16 + quad * 4) * TRP + ni * 16 + l16;
                    tw[ad] = (unsigned short)p01;
                    tw[ad + TRP] = (unsigned short)(p01 >> 16);
                    tw[ad + 2 * TRP] = (unsigned short)p23;
                    tw[ad + 3 * TRP] = (unsigned short)(p23 >> 16);
                }
            }
            // 4) store
            if (z == 0) {
#pragma unroll
                for (int c = 0; c < 4; c++) {
                    int g = c * 64 + lane;
                    int ml = g >> 3, dc = g & 7;
                    bf16x8 vv = *(const bf16x8*)&tw[ml * TRP + dc * 8];
                    *(bf16x8*)&qfb[rowbase + (size_t)(hh * 32 + ml) * DK + dc * 8] = vv;
                }
            } else {
#pragma unroll
                for (int c = 0; c < 4; c++) {
                    int ad = ((c >> 1) * 16 + l16) * TRP + (c & 1) * 32 + quad * 8;
                    bf16x8 vv = *(const bf16x8*)&tw[ad];
                    *(bf16x8*)&kfrag[tb + (size_t)(hh * 4 + c) * 512 + lane * 8] = vv;
                }
            }
        }
    }
}

// ---------------- out-projection GEMM: 128x64 tiles (2 blocks/CU), fp32 out ----------------
__global__ __launch_bounds__(256) void k_gemm_out(const unsigned short* __restrict__ A,
                                                  const unsigned short* __restrict__ Wt,
                                                  const float* __restrict__ bias,
                                                  float* __restrict__ out_f32) {
    const int K = DM;
    int m0 = blockIdx.y * 128, n0 = blockIdx.x * 64;
    __shared__ unsigned short As[128 * 32];
    __shared__ unsigned short Bs[64 * 32];
    int tid = threadIdx.x;
    int lane = tid & 63, wid = tid >> 6;
    int l16 = lane & 15, quad = lane >> 4;

    floatx4 acc[2][4] = {};

    for (int kt = 0; kt < K / 32; kt++) {
        int kk = kt * 32;
#pragma unroll
        for (int i = 0; i < 2; i++) {
            int c = i * 256 + tid;
            gl2lds16(A + (size_t)(m0 + (c >> 2)) * K + kk + (c & 3) * 8, &As[c * 8]);
        }
        gl2lds16(Wt + (size_t)(n0 + (tid >> 2)) * K + kk + (tid & 3) * 8, &Bs[tid * 8]);
        __syncthreads();
        bf16x8 af[2], bf[4];
#pragma unroll
        for (int mi = 0; mi < 2; mi++)
            af[mi] = *(const bf16x8*)&As[(wid * 32 + mi * 16 + l16) * 32 + quad * 8];
#pragma unroll
        for (int ni = 0; ni < 4; ni++)
            bf[ni] = *(const bf16x8*)&Bs[(ni * 16 + l16) * 32 + quad * 8];
#pragma unroll
        for (int mi = 0; mi < 2; mi++)
#pragma unroll
            for (int ni = 0; ni < 4; ni++)
                acc[mi][ni] = __builtin_amdgcn_mfma_f32_16x16x32_bf16(af[mi], bf[ni], acc[mi][ni], 0, 0, 0);
        __syncthreads();
    }

#pragma unroll
    for (int mi = 0; mi < 2; mi++) {
#pragma unroll
        for (int ni = 0; ni < 4; ni++) {
            int col = n0 + ni * 16 + l16;
            float bvv = bias[col];
#pragma unroll
            for (int r = 0; r < 4; r++) {
                int row = m0 + wid * 32 + mi * 16 + quad * 4 + r;
                out_f32[(size_t)row * DM + col] = acc[mi][ni][r] + bvv;
            }
        }
    }
}

// ---------------- flash attention, S^T formulation, split-K over 2 key halves ----------------
// grid: (S/128, B*H, 2). block 256 = 4 waves, each wave owns 32 q-rows (2 groups of 16).
// No-max softmax => partials are additive: write unnormalized fp32 O + L per half.
// Row-sum computed via MFMA against an all-ones B operand (idle MFMA pipe, frees VALU).
__global__ __launch_bounds__(256, 4) void k_attn(const unsigned short* __restrict__ qf,
                                                 const unsigned short* __restrict__ kfr,
                                                 const unsigned short* __restrict__ vfr,
                                                 const unsigned long long* __restrict__ mb64,
                                                 float* __restrict__ Opart,
                                                 float* __restrict__ Lpart) {
    int tid = threadIdx.x, lane = tid & 63, wid = tid >> 6;
    int l16 = lane & 15, quad = lane >> 4;
    int bh = blockIdx.y;
    int z = blockIdx.z;
    int q0 = blockIdx.x * 128 + wid * 32;
    int kt0 = z * 16;

    const unsigned short* qfb = qf + (size_t)bh * S_LEN * DK;
    const unsigned short* kbase = kfr + (size_t)bh * 32 * 4096;
    const unsigned short* vbase = vfr + (size_t)bh * 32 * 4096;

    __shared__ unsigned short Kbuf[2][4096];
    __shared__ unsigned short Plds[4][32 * PSTR];
    unsigned short* myP = Plds[wid];

    union { bf16x8 v; unsigned short u[8]; } one_u;
#pragma unroll
    for (int j = 0; j < 8; j++) one_u.u[j] = 0x3F80;  // bf16 1.0
    bf16x8 ones = one_u.v;

    // Q as B-operand: lane l16 = q-row, k = d
    bf16x8 bq[2][2];
#pragma unroll
    for (int g = 0; g < 2; g++)
#pragma unroll
        for (int ks = 0; ks < 2; ks++)
            bq[g][ks] = *(const bf16x8*)(qfb + (size_t)(q0 + g * 16 + l16) * DK + ks * 32 + quad * 8);

    gl2lds16(kbase + (size_t)kt0 * 4096 + tid * 8, &Kbuf[0][tid * 8]);
    gl2lds16(kbase + (size_t)kt0 * 4096 + 2048 + tid * 8, &Kbuf[0][2048 + tid * 8]);

    floatx4 oacc[2][4] = {};
    floatx4 lacc[2] = {};
    const unsigned long long* mq0 = mb64 + (size_t)(q0 + l16) * 32;
    const unsigned long long* mq1 = mb64 + (size_t)(q0 + 16 + l16) * 32;

    for (int lk = 0; lk < 16; lk++) {
        int kt = kt0 + lk;
        __syncthreads();   // tile kt staged (issued a full iteration ago); prev reads done
        int nb = (lk + 1) & 1;
        const unsigned short* kn = kbase + (size_t)(kt0 + ((lk + 1) & 15)) * 4096;
        gl2lds16(kn + tid * 8, &Kbuf[nb][tid * 8]);
        gl2lds16(kn + 2048 + tid * 8, &Kbuf[nb][2048 + tid * 8]);
        // V prefetch (coalesced, shared across both q-groups)
        const unsigned short* vt = vbase + (size_t)kt * 4096 + lane * 8;
        bf16x8 vf[8];
#pragma unroll
        for (int i = 0; i < 8; i++) vf[i] = *(const bf16x8*)(vt + i * 512);
        unsigned long long mw[2] = {mq0[kt], mq1[kt]};
        const unsigned short* kb = &Kbuf[lk & 1][lane * 8];
        bf16x8 kf8[8];
#pragma unroll
        for (int i = 0; i < 8; i++) kf8[i] = *(const bf16x8*)(kb + i * 512);
#pragma unroll
        for (int g = 0; g < 2; g++) {
            unsigned short* pw = myP + (g * 16 + l16) * PSTR;
#pragma unroll
            for (int kbk = 0; kbk < 4; kbk++) {
                floatx4 s = {};
                s = __builtin_amdgcn_mfma_f32_16x16x32_bf16(kf8[kbk * 2], bq[g][0], s, 0, 0, 0);
                s = __builtin_amdgcn_mfma_f32_16x16x32_bf16(kf8[kbk * 2 + 1], bq[g][1], s, 0, 0, 0);
                unsigned w = (unsigned)(mw[g] >> (kbk * 16 + quad * 4));
                float p0 = __ocml_exp2_f32((w & 1u) ? s[0] : -23.0f);
                float p1 = __ocml_exp2_f32((w & 2u) ? s[1] : -23.0f);
                float p2 = __ocml_exp2_f32((w & 4u) ? s[2] : -23.0f);
                float p3 = __ocml_exp2_f32((w & 8u) ? s[3] : -23.0f);
                *(unsigned*)&pw[kbk * 16 + quad * 4] = cvt_pk_bf16(p0, p1);
                *(unsigned*)&pw[kbk * 16 + quad * 4 + 2] = cvt_pk_bf16(p2, p3);
            }
            // P A-frags (own rows; DS ops wave-ordered)
            bf16x8 pa0 = *(const bf16x8*)&myP[(g * 16 + l16) * PSTR + quad * 8];
            bf16x8 pa1 = *(const bf16x8*)&myP[(g * 16 + l16) * PSTR + 32 + quad * 8];
            // row-sum on the MFMA pipe: l = P @ ones
            lacc[g] = __builtin_amdgcn_mfma_f32_16x16x32_bf16(pa0, ones, lacc[g], 0, 0, 0);
            lacc[g] = __builtin_amdgcn_mfma_f32_16x16x32_bf16(pa1, ones, lacc[g], 0, 0, 0);
#pragma unroll
            for (int ni = 0; ni < 4; ni++) {
                oacc[g][ni] = __builtin_amdgcn_mfma_f32_16x16x32_bf16(pa0, vf[ni * 2], oacc[g][ni], 0, 0, 0);
                oacc[g][ni] = __builtin_amdgcn_mfma_f32_16x16x32_bf16(pa1, vf[ni * 2 + 1], oacc[g][ni], 0, 0, 0);
            }
        }
    }
    // store unnormalized partials (rows of lacc match rows of oacc: q = g*16+quad*4+r)
    size_t obase = ((size_t)z * BHS + (size_t)bh * S_LEN) * DK;
    size_t lbase = (size_t)z * BHS + (size_t)bh * S_LEN;
#pragma unroll
    for (int g = 0; g < 2; g++) {
        if (l16 == 0) {
#pragma unroll
            for (int r = 0; r < 4; r++)
                Lpart[lbase + q0 + g * 16 + quad * 4 + r] = lacc[g][r];
        }
#pragma unroll
        for (int ni = 0; ni < 4; ni++) {
#pragma unroll
            for (int r = 0; r < 4; r++)
                Opart[obase + (size_t)(q0 + g * 16 + quad * 4 + r) * DK + ni * 16 + l16] = oacc[g][ni][r];
        }
    }
}

// ---------------- combine split-K partials -> ctx bf16 ----------------
__global__ __launch_bounds__(256) void k_combine(const float* __restrict__ O,
                                                 const float* __restrict__ L,
                                                 unsigned short* __restrict__ ctx) {
    int gid = blockIdx.x * 256 + threadIdx.x;   // 1M threads, 4 floats each
    size_t flat = (size_t)gid * 4;
    int row = gid >> 4;
    int d0 = (gid & 15) * 4;
    floatx4 o0 = *(const floatx4*)&O[flat];
    floatx4 o1 = *(const floatx4*)&O[(size_t)BHS * DK + flat];
    float ri = 1.0f / (L[row] + L[BHS + row]);
    int bh = row >> 11, s = row & (S_LEN - 1);
    int b = bh >> 4, h = bh & 15;
    unsigned p01 = cvt_pk_bf16((o0[0] + o1[0]) * ri, (o0[1] + o1[1]) * ri);
    unsigned p23 = cvt_pk_bf16((o0[2] + o1[2]) * ri, (o0[3] + o1[3]) * ri);
    ushort4v o;
    o[0] = (unsigned short)p01; o[1] = (unsigned short)(p01 >> 16);
    o[2] = (unsigned short)p23; o[3] = (unsigned short)(p23 >> 16);
    *(ushort4v*)&ctx[((size_t)(b * S_LEN + s)) * DM + h * DK + d0] = o;
}

// ---------------- RMSNorm ----------------
__global__ __launch_bounds__(256) void k_rmsnorm(const float* __restrict__ x,
                                                 const float* __restrict__ gamma,
                                                 float* __restrict__ out) {
    int row = blockIdx.x, tid = threadIdx.x;
    const floatx4* xr = (const floatx4*)(x + (size_t)row * DM);
    floatx4 v = xr[tid];
    float ss = v[0] * v[0] + v[1] * v[1] + v[2] * v[2] + v[3] * v[3];
#pragma unroll
    for (int off = 1; off < 64; off <<= 1) ss += __shfl_xor(ss, off);
    __shared__ float red[4];
    int lane = tid & 63, wid = tid >> 6;
    if (lane == 0) red[wid] = ss;
    __syncthreads();
    float tot = red[0] + red[1] + red[2] + red[3];
    float rms = rsqrtf(tot * (1.0f / DM) + 1e-6f);
    floatx4 g = ((const floatx4*)gamma)[tid];
    floatx4 o;
    o[0] = v[0] * rms * g[0];
    o[1] = v[1] * rms * g[1];
    o[2] = v[2] * rms * g[2];
    o[3] = v[3] * rms * g[3];
    ((floatx4*)(out + (size_t)row * DM))[tid] = o;
}

extern "C" void kernel_launch(void* const* d_in, const int* in_sizes, int n_in,
                              void* d_out, int out_size, void* d_ws, size_t ws_size,
                              hipStream_t stream) {
    const float* Q = (const float*)d_in[0];
    const float* K = (const float*)d_in[1];
    const float* V = (const float*)d_in[2];
    const int* mask = (const int*)d_in[3];
    const float* wq = (const float*)d_in[4];
    const float* bq = (const float*)d_in[5];
    const float* wk = (const float*)d_in[6];
    const float* bk = (const float*)d_in[7];
    const float* wv = (const float*)d_in[8];
    const float* bv = (const float*)d_in[9];
    const float* wo = (const float*)d_in[10];
    const float* bo = (const float*)d_in[11];
    const float* wnq = (const float*)d_in[12];
    const float* bnq = (const float*)d_in[13];
    const float* wnk = (const float*)d_in[14];
    const float* bnk = (const float*)d_in[15];
    const float* temp = (const float*)d_in[16];
    const float* gamma = (const float*)d_in[17];

    char* w = (char*)d_ws;
    size_t o = 0;
    auto alloc = [&](size_t bytes) {
        char* p = w + o;
        o += (bytes + 255) & ~(size_t)255;
        return p;
    };
    unsigned short* Qb = (unsigned short*)alloc((size_t)BS * DM * 2);
    unsigned short* Kb = (unsigned short*)alloc((size_t)BS * DM * 2);
    unsigned short* Vb = (unsigned short*)alloc((size_t)BS * DM * 2);
    unsigned short* Wqt = (unsigned short*)alloc((size_t)DM * DM * 2);
    unsigned short* Wkt = (unsigned short*)alloc((size_t)DM * DM * 2);
    unsigned short* Wvt = (unsigned short*)alloc((size_t)DM * DM * 2);
    unsigned short* Wot = (unsigned short*)alloc((size_t)DM * DM * 2);
    unsigned short* wnqt = (unsigned short*)alloc((size_t)DK * DK * 2);
    unsigned short* wnkt = (unsigned short*)alloc((size_t)DK * DK * 2);
    unsigned short* vfrag = (unsigned short*)alloc((size_t)BHS * DK * 2);
    unsigned short* qfb = (unsigned short*)alloc((size_t)BHS * DK * 2);
    unsigned short* kfrag = (unsigned short*)alloc((size_t)BHS * DK * 2);
    unsigned int* mb = (unsigned int*)alloc((size_t)S_LEN * (S_LEN / 32) * 4);
    unsigned short* ctx = (unsigned short*)alloc((size_t)BS * DM * 2);
    float* outt = (float*)alloc((size_t)BS * DM * 4);
    float* Opart = (float*)alloc((size_t)2 * BHS * DK * 4);
    float* Lpart = (float*)alloc((size_t)2 * BHS * 4);

    k_convert<<<dim3(3 * BS * DM / 4 / 256), 256, 0, stream>>>(Q, K, V, Qb, Kb, Vb);
    k_transpose<<<dim3(32, 32, 4), 256, 0, stream>>>(wq, wk, wv, wo, Wqt, Wkt, Wvt, Wot, DM);
    k_transpose<<<dim3(2, 2, 2), 256, 0, stream>>>(wnq, wnk, wnq, wnq, wnqt, wnkt, wnqt, wnqt, DK);
    k_maskpack<<<dim3(S_LEN * 64 / 256), 256, 0, stream>>>(mask, mb);

    k_gemm_qkv<<<dim3(8, 32, 3), 256, 0, stream>>>(Qb, Kb, Vb, Wqt, Wkt, Wvt,
                                                   bq, bk, bv, wnqt, wnkt, bnq, bnk, temp,
                                                   qfb, kfrag, vfrag);

    k_attn<<<dim3(S_LEN / 128, BATCH * NH, 2), 256, 0, stream>>>(
        qfb, kfrag, vfrag, (const unsigned long long*)mb, Opart, Lpart);

    k_combine<<<dim3(BHS * DK / 4 / 256), 256, 0, stream>>>(Opart, Lpart, ctx);

    k_gemm_out<<<dim3(16, 32), 256, 0, stream>>>(ctx, Wot, bo, outt);
    k_rmsnorm<<<dim3(BS), 256, 0, stream>>>(outt, gamma, (float*)d_out);
}

// Round 7
// 298.681 us; speedup vs baseline: 1.0909x; 1.0909x over previous
//
#include <hip/hip_runtime.h>
#include <hip/hip_bf16.h>
#include <math.h>

#define S_LEN 2048
#define BATCH 2
#define NH 16
#define DK 64
#define DM 1024
#define BS (BATCH * S_LEN)       /* 4096 rows */
#define BHS (BATCH * NH * S_LEN) /* 65536 head-rows */
#define TRP 72                   /* transpose-buffer pitch (shorts): 144B rows keep b128 aligned */
#define PSTR 72

using bf16x8  = __attribute__((ext_vector_type(8))) __bf16;
using floatx4 = __attribute__((ext_vector_type(4))) float;
using ushort4v = __attribute__((ext_vector_type(4))) unsigned short;

extern "C" __device__ float __ocml_exp2_f32(float);

__device__ __forceinline__ unsigned short f2bf(float f) {
    union { float f; unsigned u; } v; v.f = f;
    unsigned r = v.u + 0x7fffu + ((v.u >> 16) & 1u);
    return (unsigned short)(r >> 16);
}

// packed RNE f32x2 -> bf16x2 (single VOP3)
__device__ __forceinline__ unsigned cvt_pk_bf16(float a, float b) {
    unsigned r;
    asm("v_cvt_pk_bf16_f32 %0, %1, %2" : "=v"(r) : "v"(a), "v"(b));
    return r;
}

__device__ __forceinline__ float fast_tanh(float x) {
    float e = __ocml_exp2_f32(x * 2.8853900817779268f);
    return 1.0f - 2.0f / (e + 1.0f);
}

// async global->LDS, 16 bytes per lane. LDS dest must be wave-uniform base + lane*16.
__device__ __forceinline__ void gl2lds16(const void* g, void* l) {
    __builtin_amdgcn_global_load_lds(
        (__attribute__((address_space(1))) void*)(uintptr_t)g,
        (__attribute__((address_space(3))) void*)(uintptr_t)l,
        16, 0, 0);
}

// ---------------- prep: fp32 -> bf16 convert for Q,K,V ----------------
__global__ void k_convert(const float* __restrict__ q, const float* __restrict__ k,
                          const float* __restrict__ v,
                          unsigned short* __restrict__ qb, unsigned short* __restrict__ kb,
                          unsigned short* __restrict__ vb) {
    const int N4 = BS * DM / 4;
    int i = blockIdx.x * 256 + threadIdx.x;
    int which = i / N4;
    int off = i - which * N4;
    const floatx4* src = (const floatx4*)(which == 0 ? q : which == 1 ? k : v);
    unsigned short* dst = which == 0 ? qb : which == 1 ? kb : vb;
    floatx4 x = src[off];
    ushort4v o;
    unsigned p01 = cvt_pk_bf16(x[0], x[1]);
    unsigned p23 = cvt_pk_bf16(x[2], x[3]);
    o[0] = (unsigned short)p01; o[1] = (unsigned short)(p01 >> 16);
    o[2] = (unsigned short)p23; o[3] = (unsigned short)(p23 >> 16);
    ((ushort4v*)dst)[off] = o;
}

// ---------------- prep: transpose square fp32 matrix -> bf16 [N][K] ----------------
__global__ void k_transpose(const float* s0, const float* s1, const float* s2, const float* s3,
                            unsigned short* d0, unsigned short* d1, unsigned short* d2,
                            unsigned short* d3, int n) {
    int z = blockIdx.z;
    const float* src = z == 0 ? s0 : z == 1 ? s1 : z == 2 ? s2 : s3;
    unsigned short* dst = z == 0 ? d0 : z == 1 ? d1 : z == 2 ? d2 : d3;
    __shared__ unsigned short tile[32][33];
    int tx = threadIdx.x & 31, ty = threadIdx.x >> 5;
#pragma unroll
    for (int i = 0; i < 4; i++) {
        int y = blockIdx.y * 32 + i * 8 + ty;
        tile[i * 8 + ty][tx] = f2bf(src[(size_t)y * n + blockIdx.x * 32 + tx]);
    }
    __syncthreads();
#pragma unroll
    for (int i = 0; i < 4; i++) {
        int r = blockIdx.x * 32 + i * 8 + ty;
        dst[(size_t)r * n + blockIdx.y * 32 + tx] = tile[tx][i * 8 + ty];
    }
}

// ---------------- prep: pack mask int32 -> bitmask ----------------
__global__ void k_maskpack(const int* __restrict__ mask, unsigned int* __restrict__ mb) {
    int t = blockIdx.x * 256 + threadIdx.x;
    int row = t >> 6, w = t & 63;
    const int* p = mask + (size_t)row * S_LEN + w * 32;
    unsigned bits = 0;
#pragma unroll
    for (int i = 0; i < 32; i++) bits |= (p[i] != 0 ? 1u : 0u) << i;
    mb[t] = bits;
}

// ---------------- merged QKV projection GEMM + fused feature map ----------------
// z==0: qfb row-major [bh][s][dk], = tanh(proj@wnq+bnq) * log2e/(8*temp[h])
// z==1: kfrag fragment order, = tanh(proj@wnk+bnk)
// z==2: vfrag in PV-fragment order
__global__ __launch_bounds__(256) void k_gemm_qkv(
    const unsigned short* __restrict__ Qb, const unsigned short* __restrict__ Kb,
    const unsigned short* __restrict__ Vb,
    const unsigned short* __restrict__ Wqt, const unsigned short* __restrict__ Wkt,
    const unsigned short* __restrict__ Wvt,
    const float* __restrict__ bq, const float* __restrict__ bk, const float* __restrict__ bv,
    const unsigned short* __restrict__ wnqt, const unsigned short* __restrict__ wnkt,
    const float* __restrict__ bnq, const float* __restrict__ bnk,
    const float* __restrict__ temp,
    unsigned short* __restrict__ qfb, unsigned short* __restrict__ kfrag,
    unsigned short* __restrict__ vfrag) {
    const int K = DM;
    int z = blockIdx.z;
    const unsigned short* A  = z == 0 ? Qb  : z == 1 ? Kb  : Vb;
    const unsigned short* Wt = z == 0 ? Wqt : z == 1 ? Wkt : Wvt;
    const float* bias        = z == 0 ? bq  : z == 1 ? bk  : bv;
    int m0 = blockIdx.y * 128, n0 = blockIdx.x * 128;
    __shared__ unsigned short As[128 * 32];
    __shared__ unsigned short Bs[128 * 32];
    __shared__ unsigned short Tr[4][32 * TRP];
    int tid = threadIdx.x;
    int lane = tid & 63, wid = tid >> 6;
    int wy = wid >> 1, wx = wid & 1;
    int l16 = lane & 15, quad = lane >> 4;

    floatx4 acc[4][4] = {};

    for (int kt = 0; kt < K / 32; kt++) {
        int kk = kt * 32;
#pragma unroll
        for (int i = 0; i < 2; i++) {
            int c = i * 256 + tid;
            int row = c >> 2, seg = c & 3;
            gl2lds16(A + (size_t)(m0 + row) * K + kk + seg * 8, &As[c * 8]);
            gl2lds16(Wt + (size_t)(n0 + row) * K + kk + seg * 8, &Bs[c * 8]);
        }
        __syncthreads();
        bf16x8 af[4], bf[4];
#pragma unroll
        for (int mi = 0; mi < 4; mi++)
            af[mi] = *(const bf16x8*)&As[(wy * 64 + mi * 16 + l16) * 32 + quad * 8];
#pragma unroll
        for (int ni = 0; ni < 4; ni++)
            bf[ni] = *(const bf16x8*)&Bs[(wx * 64 + ni * 16 + l16) * 32 + quad * 8];
#pragma unroll
        for (int mi = 0; mi < 4; mi++)
#pragma unroll
            for (int ni = 0; ni < 4; ni++)
                acc[mi][ni] = __builtin_amdgcn_mfma_f32_16x16x32_bf16(af[mi], bf[ni], acc[mi][ni], 0, 0, 0);
        __syncthreads();
    }

    float bvv[4];
#pragma unroll
    for (int ni = 0; ni < 4; ni++) bvv[ni] = bias[n0 + wx * 64 + ni * 16 + l16];
    int head = (n0 + wx * 64) >> 6;
    int mbase = m0 + wy * 64;
    int b = mbase >> 11;
    int bh = b * NH + head;
    unsigned short* tw = &Tr[wid][0];

    if (z == 2) {
        int kt2 = (mbase & (S_LEN - 1)) >> 6;
        size_t tilebase = ((size_t)bh * 32 + kt2) * 4096;
#pragma unroll
        for (int hh = 0; hh < 2; hh++) {
#pragma unroll
            for (int ni2 = 0; ni2 < 2; ni2++) {
                int ni = hh * 2 + ni2;
#pragma unroll
                for (int mi = 0; mi < 4; mi++) {
                    unsigned p01 = cvt_pk_bf16(acc[mi][ni][0] + bvv[ni], acc[mi][ni][1] + bvv[ni]);
                    unsigned p23 = cvt_pk_bf16(acc[mi][ni][2] + bvv[ni], acc[mi][ni][3] + bvv[ni]);
                    int ad = (ni2 * 16 + l16) * TRP + mi * 16 + quad * 4;
                    *(unsigned*)&tw[ad] = p01;
                    *(unsigned*)&tw[ad + 2] = p23;
                }
            }
#pragma unroll
            for (int c = 0; c < 4; c++) {
                int ad = ((c >> 1) * 16 + l16) * TRP + (c & 1) * 32 + quad * 8;
                bf16x8 vv = *(const bf16x8*)&tw[ad];
                *(bf16x8*)&vfrag[tilebase + (size_t)(4 * hh + c) * 512 + lane * 8] = vv;
            }
        }
    } else {
        const unsigned short* wn = z == 0 ? wnqt : wnkt;
        const float* bn = z == 0 ? bnq : bnk;
        float sc = z == 0 ? 1.4426950408889634f / (8.0f * temp[head]) : 1.0f;
        bf16x8 wf[4][2];
        float bnv[4];
#pragma unroll
        for (int ni = 0; ni < 4; ni++) {
            bnv[ni] = bn[ni * 16 + l16];
#pragma unroll
            for (int ks = 0; ks < 2; ks++)
                wf[ni][ks] = *(const bf16x8*)(wn + (size_t)(ni * 16 + l16) * DK + ks * 32 + quad * 8);
        }
        size_t rowbase = (size_t)((size_t)bh * S_LEN + (mbase & (S_LEN - 1))) * DK;
        int kt2 = (mbase & (S_LEN - 1)) >> 6;
        size_t tb = ((size_t)bh * 32 + kt2) * 4096;
#pragma unroll
        for (int hh = 0; hh < 2; hh++) {
            // 1) projection rows (+bias) -> Tr [m][d]
#pragma unroll
            for (int mi2 = 0; mi2 < 2; mi2++) {
                int mi = hh * 2 + mi2;
#pragma unroll
                for (int ni = 0; ni < 4; ni++) {
                    unsigned p01 = cvt_pk_bf16(acc[mi][ni][0] + bvv[ni], acc[mi][ni][1] + bvv[ni]);
                    unsigned p23 = cvt_pk_bf16(acc[mi][ni][2] + bvv[ni], acc[mi][ni][3] + bvv[ni]);
                    int ad = (mi2 * 16 + quad * 4) * TRP + ni * 16 + l16;
                    tw[ad] = (unsigned short)p01;
                    tw[ad + TRP] = (unsigned short)(p01 >> 16);
                    tw[ad + 2 * TRP] = (unsigned short)p23;
                    tw[ad + 3 * TRP] = (unsigned short)(p23 >> 16);
                }
            }
            // 2) feature GEMM from Tr A-frags (own wave slice; DS ops wave-ordered)
            floatx4 facc[2][4] = {};
#pragma unroll
            for (int mg = 0; mg < 2; mg++) {
                bf16x8 af2[2];
#pragma unroll
                for (int ks = 0; ks < 2; ks++)
                    af2[ks] = *(const bf16x8*)&tw[(mg * 16 + l16) * TRP + ks * 32 + quad * 8];
#pragma unroll
                for (int ni = 0; ni < 4; ni++) {
                    facc[mg][ni] = __builtin_amdgcn_mfma_f32_16x16x32_bf16(af2[0], wf[ni][0], facc[mg][ni], 0, 0, 0);
                    facc[mg][ni] = __builtin_amdgcn_mfma_f32_16x16x32_bf16(af2[1], wf[ni][1], facc[mg][ni], 0, 0, 0);
                }
            }
            // 3) tanh(+bias)*sc -> Tr [m][d']
#pragma unroll
            for (int mg = 0; mg < 2; mg++) {
#pragma unroll
                for (int ni = 0; ni < 4; ni++) {
                    float t0 = fast_tanh(facc[mg][ni][0] + bnv[ni]) * sc;
                    float t1 = fast_tanh(facc[mg][ni][1] + bnv[ni]) * sc;
                    float t2 = fast_tanh(facc[mg][ni][2] + bnv[ni]) * sc;
                    float t3 = fast_tanh(facc[mg][ni][3] + bnv[ni]) * sc;
                    unsigned p01 = cvt_pk_bf16(t0, t1);
                    unsigned p23 = cvt_pk_bf16(t2, t3);
                    int ad = (mg * 16 + quad * 4) * TRP + ni * 16 + l16;
                    tw[ad] = (unsigned short)p01;
                    tw[ad + TRP] = (unsigned short)(p01 >> 16);
                    tw[ad + 2 * TRP] = (unsigned short)p23;
                    tw[ad + 3 * TRP] = (unsigned short)(p23 >> 16);
                }
            }
            // 4) store
            if (z == 0) {
#pragma unroll
                for (int c = 0; c < 4; c++) {
                    int g = c * 64 + lane;
                    int ml = g >> 3, dc = g & 7;
                    bf16x8 vv = *(const bf16x8*)&tw[ml * TRP + dc * 8];
                    *(bf16x8*)&qfb[rowbase + (size_t)(hh * 32 + ml) * DK + dc * 8] = vv;
                }
            } else {
#pragma unroll
                for (int c = 0; c < 4; c++) {
                    int ad = ((c >> 1) * 16 + l16) * TRP + (c & 1) * 32 + quad * 8;
                    bf16x8 vv = *(const bf16x8*)&tw[ad];
                    *(bf16x8*)&kfrag[tb + (size_t)(hh * 4 + c) * 512 + lane * 8] = vv;
                }
            }
        }
    }
}

// ---------------- out-projection GEMM: 128x64 tiles (2 blocks/CU), fp32 out ----------------
__global__ __launch_bounds__(256) void k_gemm_out(const unsigned short* __restrict__ A,
                                                  const unsigned short* __restrict__ Wt,
                                                  const float* __restrict__ bias,
                                                  float* __restrict__ out_f32) {
    const int K = DM;
    int m0 = blockIdx.y * 128, n0 = blockIdx.x * 64;
    __shared__ unsigned short As[128 * 32];
    __shared__ unsigned short Bs[64 * 32];
    int tid = threadIdx.x;
    int lane = tid & 63, wid = tid >> 6;
    int l16 = lane & 15, quad = lane >> 4;

    floatx4 acc[2][4] = {};

    for (int kt = 0; kt < K / 32; kt++) {
        int kk = kt * 32;
#pragma unroll
        for (int i = 0; i < 2; i++) {
            int c = i * 256 + tid;
            gl2lds16(A + (size_t)(m0 + (c >> 2)) * K + kk + (c & 3) * 8, &As[c * 8]);
        }
        gl2lds16(Wt + (size_t)(n0 + (tid >> 2)) * K + kk + (tid & 3) * 8, &Bs[tid * 8]);
        __syncthreads();
        bf16x8 af[2], bf[4];
#pragma unroll
        for (int mi = 0; mi < 2; mi++)
            af[mi] = *(const bf16x8*)&As[(wid * 32 + mi * 16 + l16) * 32 + quad * 8];
#pragma unroll
        for (int ni = 0; ni < 4; ni++)
            bf[ni] = *(const bf16x8*)&Bs[(ni * 16 + l16) * 32 + quad * 8];
#pragma unroll
        for (int mi = 0; mi < 2; mi++)
#pragma unroll
            for (int ni = 0; ni < 4; ni++)
                acc[mi][ni] = __builtin_amdgcn_mfma_f32_16x16x32_bf16(af[mi], bf[ni], acc[mi][ni], 0, 0, 0);
        __syncthreads();
    }

#pragma unroll
    for (int mi = 0; mi < 2; mi++) {
#pragma unroll
        for (int ni = 0; ni < 4; ni++) {
            int col = n0 + ni * 16 + l16;
            float bvv = bias[col];
#pragma unroll
            for (int r = 0; r < 4; r++) {
                int row = m0 + wid * 32 + mi * 16 + quad * 4 + r;
                out_f32[(size_t)row * DM + col] = acc[mi][ni][r] + bvv;
            }
        }
    }
}

// ---------------- flash attention, S^T formulation, 16 q-rows per wave ----------------
// grid: (S/64, B*H). block 256 = 4 waves. No split-K (partial-write traffic loses).
// lane l16 owns one q-row: 1 mask u64/lane/tile, packed b32 P writes.
// Row-sum via MFMA ones => normalization fully in-register, write ctx bf16 directly.
__global__ __launch_bounds__(256, 4) void k_attn(const unsigned short* __restrict__ qf,
                                                 const unsigned short* __restrict__ kfr,
                                                 const unsigned short* __restrict__ vfr,
                                                 const unsigned long long* __restrict__ mb64,
                                                 unsigned short* __restrict__ ctx) {
    int tid = threadIdx.x, lane = tid & 63, wid = tid >> 6;
    int l16 = lane & 15, quad = lane >> 4;
    int bh = blockIdx.y;
    int b = bh >> 4, h = bh & 15;
    int q0 = blockIdx.x * 64 + wid * 16;

    const unsigned short* qfb = qf + (size_t)bh * S_LEN * DK;
    const unsigned short* kbase = kfr + (size_t)bh * 32 * 4096;
    const unsigned short* vbase = vfr + (size_t)bh * 32 * 4096;

    __shared__ unsigned short Kbuf[2][4096];
    __shared__ unsigned short Plds[4][16 * PSTR];
    unsigned short* myP = Plds[wid];

    union { bf16x8 v; unsigned short u[8]; } one_u;
#pragma unroll
    for (int j = 0; j < 8; j++) one_u.u[j] = 0x3F80;  // bf16 1.0
    bf16x8 ones = one_u.v;

    // Q as B-operand: lane l16 = q-row, k = d
    bf16x8 bq[2];
#pragma unroll
    for (int ks = 0; ks < 2; ks++)
        bq[ks] = *(const bf16x8*)(qfb + (size_t)(q0 + l16) * DK + ks * 32 + quad * 8);

    gl2lds16(kbase + tid * 8, &Kbuf[0][tid * 8]);
    gl2lds16(kbase + 2048 + tid * 8, &Kbuf[0][2048 + tid * 8]);

    floatx4 oacc[4] = {};
    floatx4 lacc = {};
    const unsigned long long* mq = mb64 + (size_t)(q0 + l16) * 32;

    for (int kt = 0; kt < 32; kt++) {
        __syncthreads();   // tile kt staged (issued a full iteration ago); prev reads done
        int nb = (kt + 1) & 1;
        const unsigned short* kn = kbase + (size_t)((kt + 1) & 31) * 4096;
        gl2lds16(kn + tid * 8, &Kbuf[nb][tid * 8]);
        gl2lds16(kn + 2048 + tid * 8, &Kbuf[nb][2048 + tid * 8]);
        // V prefetch (coalesced, consumed after softmax)
        const unsigned short* vt = vbase + (size_t)kt * 4096 + lane * 8;
        bf16x8 vf[8];
#pragma unroll
        for (int i = 0; i < 8; i++) vf[i] = *(const bf16x8*)(vt + i * 512);
        unsigned long long mw = mq[kt];
        const unsigned short* kb = &Kbuf[kt & 1][lane * 8];
        bf16x8 kf8[8];
#pragma unroll
        for (int i = 0; i < 8; i++) kf8[i] = *(const bf16x8*)(kb + i * 512);
        unsigned short* pw = myP + l16 * PSTR;
#pragma unroll
        for (int kbk = 0; kbk < 4; kbk++) {
            floatx4 s = {};
            s = __builtin_amdgcn_mfma_f32_16x16x32_bf16(kf8[kbk * 2], bq[0], s, 0, 0, 0);
            s = __builtin_amdgcn_mfma_f32_16x16x32_bf16(kf8[kbk * 2 + 1], bq[1], s, 0, 0, 0);
            unsigned w = (unsigned)(mw >> (kbk * 16 + quad * 4));
            float p0 = __ocml_exp2_f32((w & 1u) ? s[0] : -23.0f);
            float p1 = __ocml_exp2_f32((w & 2u) ? s[1] : -23.0f);
            float p2 = __ocml_exp2_f32((w & 4u) ? s[2] : -23.0f);
            float p3 = __ocml_exp2_f32((w & 8u) ? s[3] : -23.0f);
            *(unsigned*)&pw[kbk * 16 + quad * 4] = cvt_pk_bf16(p0, p1);
            *(unsigned*)&pw[kbk * 16 + quad * 4 + 2] = cvt_pk_bf16(p2, p3);
        }
        // P A-frags (own rows; DS ops wave-ordered)
        bf16x8 pa0 = *(const bf16x8*)&myP[l16 * PSTR + quad * 8];
        bf16x8 pa1 = *(const bf16x8*)&myP[l16 * PSTR + 32 + quad * 8];
        // row-sum on the MFMA pipe: l = P @ ones
        lacc = __builtin_amdgcn_mfma_f32_16x16x32_bf16(pa0, ones, lacc, 0, 0, 0);
        lacc = __builtin_amdgcn_mfma_f32_16x16x32_bf16(pa1, ones, lacc, 0, 0, 0);
#pragma unroll
        for (int ni = 0; ni < 4; ni++) {
            oacc[ni] = __builtin_amdgcn_mfma_f32_16x16x32_bf16(pa0, vf[ni * 2], oacc[ni], 0, 0, 0);
            oacc[ni] = __builtin_amdgcn_mfma_f32_16x16x32_bf16(pa1, vf[ni * 2 + 1], oacc[ni], 0, 0, 0);
        }
    }
    // epilogue: lacc rows align with oacc rows (q = quad*4+r) -> no cross-lane work
    float inv[4];
#pragma unroll
    for (int r = 0; r < 4; r++) inv[r] = 1.0f / lacc[r];
#pragma unroll
    for (int ni = 0; ni < 4; ni++) {
        int d = ni * 16 + l16;
#pragma unroll
        for (int r = 0; r < 4; r++) {
            int s = q0 + quad * 4 + r;
            ctx[(size_t)(b * S_LEN + s) * DM + h * DK + d] = f2bf(oacc[ni][r] * inv[r]);
        }
    }
}

// ---------------- RMSNorm ----------------
__global__ __launch_bounds__(256) void k_rmsnorm(const float* __restrict__ x,
                                                 const float* __restrict__ gamma,
                                                 float* __restrict__ out) {
    int row = blockIdx.x, tid = threadIdx.x;
    const floatx4* xr = (const floatx4*)(x + (size_t)row * DM);
    floatx4 v = xr[tid];
    float ss = v[0] * v[0] + v[1] * v[1] + v[2] * v[2] + v[3] * v[3];
#pragma unroll
    for (int off = 1; off < 64; off <<= 1) ss += __shfl_xor(ss, off);
    __shared__ float red[4];
    int lane = tid & 63, wid = tid >> 6;
    if (lane == 0) red[wid] = ss;
    __syncthreads();
    float tot = red[0] + red[1] + red[2] + red[3];
    float rms = rsqrtf(tot * (1.0f / DM) + 1e-6f);
    floatx4 g = ((const floatx4*)gamma)[tid];
    floatx4 o;
    o[0] = v[0] * rms * g[0];
    o[1] = v[1] * rms * g[1];
    o[2] = v[2] * rms * g[2];
    o[3] = v[3] * rms * g[3];
    ((floatx4*)(out + (size_t)row * DM))[tid] = o;
}

extern "C" void kernel_launch(void* const* d_in, const int* in_sizes, int n_in,
                              void* d_out, int out_size, void* d_ws, size_t ws_size,
                              hipStream_t stream) {
    const float* Q = (const float*)d_in[0];
    const float* K = (const float*)d_in[1];
    const float* V = (const float*)d_in[2];
    const int* mask = (const int*)d_in[3];
    const float* wq = (const float*)d_in[4];
    const float* bq = (const float*)d_in[5];
    const float* wk = (const float*)d_in[6];
    const float* bk = (const float*)d_in[7];
    const float* wv = (const float*)d_in[8];
    const float* bv = (const float*)d_in[9];
    const float* wo = (const float*)d_in[10];
    const float* bo = (const float*)d_in[11];
    const float* wnq = (const float*)d_in[12];
    const float* bnq = (const float*)d_in[13];
    const float* wnk = (const float*)d_in[14];
    const float* bnk = (const float*)d_in[15];
    const float* temp = (const float*)d_in[16];
    const float* gamma = (const float*)d_in[17];

    char* w = (char*)d_ws;
    size_t o = 0;
    auto alloc = [&](size_t bytes) {
        char* p = w + o;
        o += (bytes + 255) & ~(size_t)255;
        return p;
    };
    unsigned short* Qb = (unsigned short*)alloc((size_t)BS * DM * 2);
    unsigned short* Kb = (unsigned short*)alloc((size_t)BS * DM * 2);
    unsigned short* Vb = (unsigned short*)alloc((size_t)BS * DM * 2);
    unsigned short* Wqt = (unsigned short*)alloc((size_t)DM * DM * 2);
    unsigned short* Wkt = (unsigned short*)alloc((size_t)DM * DM * 2);
    unsigned short* Wvt = (unsigned short*)alloc((size_t)DM * DM * 2);
    unsigned short* Wot = (unsigned short*)alloc((size_t)DM * DM * 2);
    unsigned short* wnqt = (unsigned short*)alloc((size_t)DK * DK * 2);
    unsigned short* wnkt = (unsigned short*)alloc((size_t)DK * DK * 2);
    unsigned short* vfrag = (unsigned short*)alloc((size_t)BHS * DK * 2);
    unsigned short* qfb = (unsigned short*)alloc((size_t)BHS * DK * 2);
    unsigned short* kfrag = (unsigned short*)alloc((size_t)BHS * DK * 2);
    unsigned int* mb = (unsigned int*)alloc((size_t)S_LEN * (S_LEN / 32) * 4);
    unsigned short* ctx = (unsigned short*)alloc((size_t)BS * DM * 2);
    float* outt = (float*)alloc((size_t)BS * DM * 4);

    k_convert<<<dim3(3 * BS * DM / 4 / 256), 256, 0, stream>>>(Q, K, V, Qb, Kb, Vb);
    k_transpose<<<dim3(32, 32, 4), 256, 0, stream>>>(wq, wk, wv, wo, Wqt, Wkt, Wvt, Wot, DM);
    k_transpose<<<dim3(2, 2, 2), 256, 0, stream>>>(wnq, wnk, wnq, wnq, wnqt, wnkt, wnqt, wnqt, DK);
    k_maskpack<<<dim3(S_LEN * 64 / 256), 256, 0, stream>>>(mask, mb);

    k_gemm_qkv<<<dim3(8, 32, 3), 256, 0, stream>>>(Qb, Kb, Vb, Wqt, Wkt, Wvt,
                                                   bq, bk, bv, wnqt, wnkt, bnq, bnk, temp,
                                                   qfb, kfrag, vfrag);

    k_attn<<<dim3(S_LEN / 64, BATCH * NH), 256, 0, stream>>>(
        qfb, kfrag, vfrag, (const unsigned long long*)mb, ctx);

    k_gemm_out<<<dim3(16, 32), 256, 0, stream>>>(ctx, Wot, bo, outt);
    k_rmsnorm<<<dim3(BS), 256, 0, stream>>>(outt, gamma, (float*)d_out);
}